// Round 10
// baseline (190.995 us; speedup 1.0000x reference)
//
#include <hip/hip_runtime.h>
#include <math.h>

typedef __attribute__((ext_vector_type(8))) short short8;
typedef __attribute__((ext_vector_type(4))) float f32x4;
typedef __attribute__((ext_vector_type(4))) unsigned short ushort4v;

#define D_MODEL 768
#define NH      12
#define DK      64
#define SEQ     1024
#define NB      8
#define MTOT    (NB*SEQ)                  // 8192
#define NELT    ((size_t)MTOT*D_MODEL)    // 6291456
#define WELT    ((size_t)D_MODEL*D_MODEL) // 589824

__device__ __forceinline__ unsigned short f2bf(float f) {
    unsigned int u = __builtin_bit_cast(unsigned int, f);
    unsigned int r = (u + 0x7FFFu + ((u >> 16) & 1u)) >> 16;   // RNE
    return (unsigned short)r;
}
__device__ __forceinline__ float bf2f(unsigned short h) {
    return __builtin_bit_cast(float, ((unsigned int)h) << 16);
}
__device__ __forceinline__ void gload_lds16(const void* g, void* lds) {
    __builtin_amdgcn_global_load_lds(
        (const __attribute__((address_space(1))) unsigned int*)g,
        (__attribute__((address_space(3))) unsigned int*)lds, 16, 0, 0);
}

// ---------------------------------------------------------------------------
// fp32 -> bf16 convert: the 4 weight matrices only (small)
// ---------------------------------------------------------------------------
__global__ __launch_bounds__(256) void cvt_w(
    const float* __restrict__ a, const float* __restrict__ b,
    const float* __restrict__ c, const float* __restrict__ e,
    unsigned short* __restrict__ oa, unsigned short* __restrict__ ob,
    unsigned short* __restrict__ oc, unsigned short* __restrict__ oe)
{
    size_t i = (size_t)blockIdx.x * 256 + threadIdx.x;
    const size_t per = WELT / 8;
    const float* s; unsigned short* d; size_t l;
    if (i < per)        { s = a; d = oa; l = i; }
    else if (i < 2*per) { s = b; d = ob; l = i - per; }
    else if (i < 3*per) { s = c; d = oc; l = i - 2*per; }
    else                { s = e; d = oe; l = i - 3*per; }
    const float4* sp = (const float4*)(s + l*8);
    float4 v0 = sp[0], v1 = sp[1];
    short8 o;
    o[0]=(short)f2bf(v0.x); o[1]=(short)f2bf(v0.y); o[2]=(short)f2bf(v0.z); o[3]=(short)f2bf(v0.w);
    o[4]=(short)f2bf(v1.x); o[5]=(short)f2bf(v1.y); o[6]=(short)f2bf(v1.z); o[7]=(short)f2bf(v1.w);
    *(short8*)(d + l*8) = o;
}

// ---------------------------------------------------------------------------
// Merged projection GEMM, fused fp32->bf16 on A (reg-staged), XCD-aware 1D
// grid: xcd = bid&7; within an XCD, n iterates fastest over its (m,z) tiles,
// so all 6 consumers of an A-tile share one L2.
// z = 0: Qp = (q@wq^T + bq)*0.125   (bf16 [8192][768])
// z = 1: Kp =  k@wk^T + bk          (bf16 [8192][768])
// z = 2: Vt = (v@wv^T + bv)^T       (bf16 [B,H,DK,SEQ])
// ---------------------------------------------------------------------------
#define BM 128
#define BN 128
#define BKG 64

__global__ __launch_bounds__(256) void proj_gemm(
    const float* __restrict__ Aq, const float* __restrict__ Ak, const float* __restrict__ Av,
    const unsigned short* __restrict__ Wq, const unsigned short* __restrict__ Wk,
    const unsigned short* __restrict__ Wv,
    const float* __restrict__ bq, const float* __restrict__ bk, const float* __restrict__ bv,
    unsigned short* __restrict__ Qp, unsigned short* __restrict__ Kp,
    unsigned short* __restrict__ Vtp)
{
    __shared__ unsigned short As[BM*BKG];
    __shared__ unsigned short Bs[BN*BKG];
    const int tid = threadIdx.x;
    const int lane = tid & 63, wid = tid >> 6;
    const int wr = wid >> 1, wc = wid & 1;

    // XCD-aware decode: 1152 = 8 xcd x 24 mz x 6 n
    const int bid = blockIdx.x;
    const int xcd = bid & 7;
    const int j = bid >> 3;          // 0..143
    const int mzL = j / 6, n = j % 6;
    const int mz = xcd * 24 + mzL;   // 0..191
    const int z = mz >> 6;           // /64
    const int m0 = (mz & 63) * BM, n0 = n * BN;

    const float* A          = (z == 0) ? Aq : (z == 1) ? Ak : Av;
    const unsigned short* W = (z == 0) ? Wq : (z == 1) ? Wk : Wv;
    const float* bias       = (z == 0) ? bq : (z == 1) ? bk : bv;

    f32x4 acc[4][4];
    #pragma unroll
    for (int i = 0; i < 4; ++i)
        #pragma unroll
        for (int jj = 0; jj < 4; ++jj) acc[i][jj] = (f32x4)(0.f);

    // A reg staging: thread t owns row t>>1, 32-col half (t&1)
    const int arow = tid >> 1, ahalf = (tid & 1) * 32;
    float areg[32];
    auto aload = [&](int k0) {
        const float* src = A + (size_t)(m0 + arow)*D_MODEL + k0 + ahalf;
        #pragma unroll
        for (int i = 0; i < 8; ++i)
            *(float4*)&areg[i*4] = *(const float4*)(src + i*4);
    };
    auto astore = [&]() {
        #pragma unroll
        for (int jj = 0; jj < 4; ++jj) {
            int oct = (ahalf >> 3) + jj;
            short8 v;
            #pragma unroll
            for (int e = 0; e < 8; ++e) v[e] = (short)f2bf(areg[jj*8 + e]);
            *(short8*)&As[arow*64 + ((oct ^ (arow&7)) << 3)] = v;
        }
    };

    aload(0);
    for (int k0 = 0; k0 < D_MODEL; k0 += BKG) {
        __syncthreads();   // previous tile fully consumed
        astore();
        #pragma unroll
        for (int jj = 0; jj < 4; ++jj) {
            int p = ((wid*4 + jj) << 9) + lane*8;
            int row = p >> 6, off = p & 63;
            const unsigned short* srcB = W + (size_t)(n0+row)*D_MODEL + k0 + (off ^ ((row&7)<<3));
            gload_lds16(srcB, &Bs[(wid*4 + jj) << 9]);
        }
        __syncthreads();
        if (k0 + BKG < D_MODEL) aload(k0 + BKG);
        #pragma unroll
        for (int ks = 0; ks < 2; ++ks) {
            short8 af[4], bf8[4];
            #pragma unroll
            for (int mi = 0; mi < 4; ++mi) {
                int row = wr*64 + mi*16 + (lane & 15);
                af[mi] = *(const short8*)&As[row*BKG + ((ks*32 + (lane>>4)*8) ^ ((row&7)<<3))];
            }
            #pragma unroll
            for (int ni = 0; ni < 4; ++ni) {
                int row = wc*64 + ni*16 + (lane & 15);
                bf8[ni] = *(const short8*)&Bs[row*BKG + ((ks*32 + (lane>>4)*8) ^ ((row&7)<<3))];
            }
            #pragma unroll
            for (int mi = 0; mi < 4; ++mi)
                #pragma unroll
                for (int ni = 0; ni < 4; ++ni)
                    acc[mi][ni] = __builtin_amdgcn_mfma_f32_16x16x32_bf16(af[mi], bf8[ni], acc[mi][ni], 0, 0, 0);
        }
    }

    float bv4[4];
    #pragma unroll
    for (int ni = 0; ni < 4; ++ni) bv4[ni] = bias[n0 + wc*64 + ni*16 + (lane & 15)];

    if (z < 2) {
        unsigned short* C = (z == 0) ? Qp : Kp;
        const float scale = (z == 0) ? 0.125f : 1.0f;
        #pragma unroll
        for (int mi = 0; mi < 4; ++mi)
            #pragma unroll
            for (int ni = 0; ni < 4; ++ni) {
                int col = n0 + wc*64 + ni*16 + (lane & 15);
                int rbase = m0 + wr*64 + mi*16 + ((lane>>4)<<2);
                #pragma unroll
                for (int jj = 0; jj < 4; ++jj)
                    C[(size_t)(rbase+jj)*D_MODEL + col] = f2bf((acc[mi][ni][jj] + bv4[ni]) * scale);
            }
    } else {
        #pragma unroll
        for (int mi = 0; mi < 4; ++mi)
            #pragma unroll
            for (int ni = 0; ni < 4; ++ni) {
                int col = n0 + wc*64 + ni*16 + (lane & 15);
                int hh = col >> 6, dd = col & 63;
                int mrow = m0 + wr*64 + mi*16 + ((lane>>4)<<2);
                int bb = mrow >> 10, ss = mrow & (SEQ-1);
                ushort4v pk;
                #pragma unroll
                for (int jj = 0; jj < 4; ++jj) pk[jj] = f2bf(acc[mi][ni][jj] + bv4[ni]);
                *(ushort4v*)&Vtp[((size_t)(bb*NH + hh)*DK + dd)*SEQ + ss] = pk;
            }
    }
}

// ---------------------------------------------------------------------------
// Final GEMM: out_fp32 = Aop(bf16) @ wo^T + bo
// ---------------------------------------------------------------------------
__global__ __launch_bounds__(256) void gemm_out(
    const unsigned short* __restrict__ A, const unsigned short* __restrict__ W,
    const float* __restrict__ bias, float* __restrict__ C)
{
    __shared__ unsigned short As[BM*BKG];
    __shared__ unsigned short Bs[BN*BKG];
    const int tid = threadIdx.x;
    const int lane = tid & 63, wid = tid >> 6;
    const int wr = wid >> 1, wc = wid & 1;
    const int m0 = blockIdx.y * BM, n0 = blockIdx.x * BN;

    f32x4 acc[4][4];
    #pragma unroll
    for (int i = 0; i < 4; ++i)
        #pragma unroll
        for (int j = 0; j < 4; ++j) acc[i][j] = (f32x4)(0.f);

    for (int k0 = 0; k0 < D_MODEL; k0 += BKG) {
        __syncthreads();
        #pragma unroll
        for (int j = 0; j < 4; ++j) {
            int p = ((wid*4 + j) << 9) + lane*8;
            int row = p >> 6, off = p & 63;
            const unsigned short* srcA = A + (size_t)(m0+row)*D_MODEL + k0 + (off ^ ((row&7)<<3));
            gload_lds16(srcA, &As[(wid*4 + j) << 9]);
            const unsigned short* srcB = W + (size_t)(n0+row)*D_MODEL + k0 + (off ^ ((row&7)<<3));
            gload_lds16(srcB, &Bs[(wid*4 + j) << 9]);
        }
        __syncthreads();
        #pragma unroll
        for (int ks = 0; ks < 2; ++ks) {
            short8 af[4], bf8[4];
            #pragma unroll
            for (int mi = 0; mi < 4; ++mi) {
                int row = wr*64 + mi*16 + (lane & 15);
                af[mi] = *(const short8*)&As[row*BKG + ((ks*32 + (lane>>4)*8) ^ ((row&7)<<3))];
            }
            #pragma unroll
            for (int ni = 0; ni < 4; ++ni) {
                int row = wc*64 + ni*16 + (lane & 15);
                bf8[ni] = *(const short8*)&Bs[row*BKG + ((ks*32 + (lane>>4)*8) ^ ((row&7)<<3))];
            }
            #pragma unroll
            for (int mi = 0; mi < 4; ++mi)
                #pragma unroll
                for (int ni = 0; ni < 4; ++ni)
                    acc[mi][ni] = __builtin_amdgcn_mfma_f32_16x16x32_bf16(af[mi], bf8[ni], acc[mi][ni], 0, 0, 0);
        }
    }

    float bv4[4];
    #pragma unroll
    for (int ni = 0; ni < 4; ++ni) bv4[ni] = bias[n0 + wc*64 + ni*16 + (lane & 15)];

    #pragma unroll
    for (int mi = 0; mi < 4; ++mi)
        #pragma unroll
        for (int ni = 0; ni < 4; ++ni) {
            int col = n0 + wc*64 + ni*16 + (lane & 15);
            int rbase = m0 + wr*64 + mi*16 + ((lane>>4)<<2);
            #pragma unroll
            for (int j = 0; j < 4; ++j)
                C[(size_t)(rbase+j)*D_MODEL + col] = acc[mi][ni][j] + bv4[ni];
        }
}

// ---------------------------------------------------------------------------
// Flash attention — exact round-7 verified body (75.3 us).
// Conv folded into Q~, swapped-operand MFMA, online softmax.
// ---------------------------------------------------------------------------
#define KVB 64
#define NCH (SEQ/KVB)   // 16

__global__ __launch_bounds__(512, 4) void attn_flash(
    const unsigned short* __restrict__ Qp,   // [8192][768] bf16, scale folded
    const unsigned short* __restrict__ Kp,   // [8192][768] bf16
    const unsigned short* __restrict__ Vt,   // [96][64][1024] bf16
    const float* __restrict__ CW,
    unsigned short* __restrict__ Aop)        // [8192][768] bf16
{
    __shared__ unsigned short Ks[2][66*64];  // 16.5 KB (halo rows k-1..k+64)
    __shared__ unsigned short Vs[2][64*64];  // 16 KB  V^T chunk [64d][64k]
    __shared__ unsigned short UB[130*64];    // 16.25 KB: Qstage, then 8x2KB P

    const int tid = threadIdx.x;
    const int lane = tid & 63, wid = tid >> 6;
    const int lq = lane & 15, lg = lane >> 4;

    // XCD-aware bijective swizzle: 768 = 8 XCDs x 96
    const int bid = blockIdx.x;
    const int sw = (bid & 7) * 96 + (bid >> 3);
    const int q0 = (sw & 7) * 128;
    const int bh = sw >> 3;
    const int h = bh % NH, b = bh / NH;

    float wcv[9];
    #pragma unroll
    for (int i = 0; i < 9; ++i) wcv[i] = CW[h*9 + i];

    const unsigned short* KpB = Kp + (size_t)b*SEQ*D_MODEL + h*DK;
    const unsigned short* QpB = Qp + (size_t)b*SEQ*D_MODEL + h*DK;
    const char* VtB = (const char*)Vt + (size_t)bh*DK*SEQ*2;

    // ---- K chunk stage (66 rows = keys ck*64-1 .. ck*64+64), reg-staged ----
    short8 kr0, kr1;
    auto kload = [&](int ck) {
        { int r = tid >> 3, oct = tid & 7;
          int gk = ck*KVB - 1 + r;
          short8 v = (short8)0;
          if (gk >= 0 && gk < SEQ) v = *(const short8*)&KpB[(size_t)gk*D_MODEL + oct*8];
          kr0 = v; }
        if (tid < 16) {
          int r = 64 + (tid >> 3), oct = tid & 7;
          int gk = ck*KVB - 1 + r;
          short8 v = (short8)0;
          if (gk >= 0 && gk < SEQ) v = *(const short8*)&KpB[(size_t)gk*D_MODEL + oct*8];
          kr1 = v; }
    };
    auto kstore = [&](int buf) {
        { int r = tid >> 3, oct = tid & 7;
          *(short8*)&Ks[buf][r*64 + ((oct ^ (r&7)) << 3)] = kr0; }
        if (tid < 16) {
          int r = 64 + (tid >> 3), oct = tid & 7;
          *(short8*)&Ks[buf][r*64 + ((oct ^ (r&7)) << 3)] = kr1; }
    };
    // ---- V^T chunk stage via global_load_lds (linear dest, preswz src) ----
    auto vstage = [&](int ck, int buf) {
        int p = tid * 16;                 // byte pos in 8 KB
        int row = p >> 7, off = p & 127;  // 128 B per d-row (64 keys)
        const char* src = VtB + ((size_t)row*SEQ + ck*KVB)*2 + (off ^ ((row&7)<<4));
        gload_lds16(src, (char*)Vs[buf] + p);
    };

    kload(0);

    // ---- stage Q rows q0-1 .. q0+128 into UB (zero OOB) ----
    {
        short8 qs0 = (short8)0, qs1 = (short8)0, qs2 = (short8)0;
        int r0 = tid >> 3, o0 = tid & 7;
        int g0 = q0 - 1 + r0;
        if (g0 >= 0 && g0 < SEQ) qs0 = *(const short8*)&QpB[(size_t)g0*D_MODEL + o0*8];
        int r1 = (512 + tid) >> 3, o1 = tid & 7;
        int g1 = q0 - 1 + r1;
        if (g1 >= 0 && g1 < SEQ) qs1 = *(const short8*)&QpB[(size_t)g1*D_MODEL + o1*8];
        int r2 = 0, o2 = 0, g2 = -1;
        if (tid < 16) {
            r2 = (1024 + tid) >> 3; o2 = tid & 7;
            g2 = q0 - 1 + r2;
            if (g2 >= 0 && g2 < SEQ) qs2 = *(const short8*)&QpB[(size_t)g2*D_MODEL + o2*8];
        }
        *(short8*)&UB[r0*64 + ((o0 ^ (r0&7)) << 3)] = qs0;
        *(short8*)&UB[r1*64 + ((o1 ^ (r1&7)) << 3)] = qs1;
        if (tid < 16) *(short8*)&UB[r2*64 + ((o2 ^ (r2&7)) << 3)] = qs2;
    }
    __syncthreads();

    // ---- build Q~ B-fragments in regs: q = lane&15, d-octs ks*32+lg*8 ----
    short8 qtf0[2], qtf1[2], qtf2[2];
    {
        int r0 = wid*16 + lq;     // Qstage row of Q[q-1]
        #pragma unroll
        for (int ks = 0; ks < 2; ++ks) {
            int oct = ks*4 + lg;
            int ra = r0, rb = r0 + 1, rc = r0 + 2;
            short8 am = *(const short8*)&UB[ra*64 + ((oct ^ (ra&7)) << 3)];
            short8 ac = *(const short8*)&UB[rb*64 + ((oct ^ (rb&7)) << 3)];
            short8 ap = *(const short8*)&UB[rc*64 + ((oct ^ (rc&7)) << 3)];
            short8 f0, f1, f2;
            #pragma unroll
            for (int j = 0; j < 8; ++j) {
                float fm = bf2f((unsigned short)am[j]);
                float fc = bf2f((unsigned short)ac[j]);
                float fp = bf2f((unsigned short)ap[j]);
                float t0 = fc - (wcv[1]*fm + wcv[4]*fc + wcv[7]*fp);
                float t1 = -(wcv[0]*fm + wcv[3]*fc + wcv[6]*fp);
                float t2 = -(wcv[2]*fm + wcv[5]*fc + wcv[8]*fp);
                f0[j] = (short)f2bf(t0);
                f1[j] = (short)f2bf(t1);
                f2[j] = (short)f2bf(t2);
            }
            qtf0[ks] = f0; qtf1[ks] = f1; qtf2[ks] = f2;
        }
    }
    kstore(0);
    vstage(0, 0);
    __syncthreads();

    unsigned short* Pw = &UB[wid * 1024];   // per-warp [16 q][64 k]

    float m = -1e30f, l = 0.f;
    f32x4 oac[4];
    #pragma unroll
    for (int dt = 0; dt < 4; ++dt) oac[dt] = (f32x4)(0.f);

    int cur = 0;
    for (int ck = 0; ck < NCH; ++ck) {
        if (ck < NCH-1) { kload(ck+1); vstage(ck+1, cur^1); }

        // ---- QK~^T: 4 k-tiles of 16; slot pairing K[k+{0,-1,+1}] via halo ----
        f32x4 st[4];
        #pragma unroll
        for (int t = 0; t < 4; ++t) {
            f32x4 s = (f32x4)(0.f);
            #pragma unroll
            for (int ks = 0; ks < 2; ++ks) {
                int oct = ks*4 + lg;
                int ar0 = t*16 + lq + 1;   // slot0 (Q-D1) -> K[k]
                short8 a0 = *(const short8*)&Ks[cur][ar0*64 + ((oct ^ (ar0&7)) << 3)];
                s = __builtin_amdgcn_mfma_f32_16x16x32_bf16(a0, qtf0[ks], s, 0, 0, 0);
                int ar1 = t*16 + lq;       // slot1 (-D0) -> K[k-1]
                short8 a1 = *(const short8*)&Ks[cur][ar1*64 + ((oct ^ (ar1&7)) << 3)];
                s = __builtin_amdgcn_mfma_f32_16x16x32_bf16(a1, qtf1[ks], s, 0, 0, 0);
                int ar2 = t*16 + lq + 2;   // slot2 (-D2) -> K[k+1]
                short8 a2 = *(const short8*)&Ks[cur][ar2*64 + ((oct ^ (ar2&7)) << 3)];
                s = __builtin_amdgcn_mfma_f32_16x16x32_bf16(a2, qtf2[ks], s, 0, 0, 0);
            }
            st[t] = s;
        }

        // ---- online softmax (q = lane&15; lanes {l,l^16,l^32,l^48} share q) ----
        float tmax = -1e30f;
        #pragma unroll
        for (int t = 0; t < 4; ++t)
            #pragma unroll
            for (int j = 0; j < 4; ++j) tmax = fmaxf(tmax, st[t][j]);
        tmax = fmaxf(tmax, __shfl_xor(tmax, 16));
        tmax = fmaxf(tmax, __shfl_xor(tmax, 32));
        float mn = fmaxf(m, tmax);
        float r = __expf(m - mn);
        float lsum = 0.f;
        #pragma unroll
        for (int t = 0; t < 4; ++t)
            #pragma unroll
            for (int j = 0; j < 4; ++j) {
                float e = __expf(st[t][j] - mn);
                st[t][j] = e;
                lsum += e;
            }
        lsum += __shfl_xor(lsum, 16);
        lsum += __shfl_xor(lsum, 32);
        l = l * r + lsum;
        m = mn;
        #pragma unroll
        for (int dt = 0; dt < 4; ++dt)
            #pragma unroll
            for (int j = 0; j < 4; ++j) oac[dt][j] *= r;

        // ---- P -> per-warp LDS (k-consecutive packs), then PV ----
        #pragma unroll
        for (int t = 0; t < 4; ++t) {
            ushort4v pk;
            #pragma unroll
            for (int j = 0; j < 4; ++j) pk[j] = f2bf(st[t][j]);
            *(ushort4v*)&Pw[lq*64 + ((t*16 + lg*4) ^ ((lq&7)<<3))] = pk;
        }
        #pragma unroll
        for (int kk = 0; kk < 2; ++kk) {
            short8 p8 = *(const short8*)&Pw[lq*64 + ((kk*32 + lg*8) ^ ((lq&7)<<3))];
            #pragma unroll
            for (int dt = 0; dt < 4; ++dt) {
                int vr = dt*16 + lq;
                int voct = kk*4 + lg;
                short8 v8 = *(const short8*)&Vs[cur][vr*64 + ((voct ^ (vr&7)) << 3)];
                oac[dt] = __builtin_amdgcn_mfma_f32_16x16x32_bf16(v8, p8, oac[dt], 0, 0, 0);
            }
        }

        if (ck < NCH-1) kstore(cur^1);
        __syncthreads();
        cur ^= 1;
    }

    // ---- epilogue: O^T col = q = lane&15; divide by l; write 4x8B ----
    float invl = 1.0f / l;
    int qg = q0 + wid*16 + lq;
    #pragma unroll
    for (int dt = 0; dt < 4; ++dt) {
        ushort4v o;
        #pragma unroll
        for (int j = 0; j < 4; ++j) o[j] = f2bf(oac[dt][j] * invl);
        *(ushort4v*)&Aop[(size_t)(b*SEQ + qg)*D_MODEL + h*DK + dt*16 + lg*4] = o;
    }
}

// ---------------------------------------------------------------------------
extern "C" void kernel_launch(void* const* d_in, const int* in_sizes, int n_in,
                              void* d_out, int out_size, void* d_ws, size_t ws_size,
                              hipStream_t stream)
{
    const float* q  = (const float*)d_in[0];
    const float* k  = (const float*)d_in[1];
    const float* v  = (const float*)d_in[2];
    const float* wq = (const float*)d_in[3];
    const float* bq = (const float*)d_in[4];
    const float* wk = (const float*)d_in[5];
    const float* bk = (const float*)d_in[6];
    const float* wv = (const float*)d_in[7];
    const float* bv = (const float*)d_in[8];
    const float* wo = (const float*)d_in[9];
    const float* bo = (const float*)d_in[10];
    const float* cw = (const float*)d_in[11];

    unsigned short* wqb = (unsigned short*)d_ws;
    unsigned short* wkb = wqb + WELT;
    unsigned short* wvb = wkb + WELT;
    unsigned short* wob = wvb + WELT;
    unsigned short* Qp  = wob + WELT;
    unsigned short* Kp  = Qp  + NELT;
    unsigned short* Vtp = Kp  + NELT;
    unsigned short* Aop = Vtp + NELT;

    cvt_w<<<(int)(4*WELT/8/256), 256, 0, stream>>>(wq, wk, wv, wo, wqb, wkb, wvb, wob);

    proj_gemm<<<dim3(1152), 256, 0, stream>>>(q, k, v, wqb, wkb, wvb,
                                              bq, bk, bv, Qp, Kp, Vtp);

    attn_flash<<<dim3(768), 512, 0, stream>>>(Qp, Kp, Vtp, cw, Aop);

    gemm_out<<<dim3(D_MODEL/BN, MTOT/BM), 256, 0, stream>>>(Aop, wob, bo, (float*)d_out);
}

// Round 11
// 172.179 us; speedup vs baseline: 1.1093x; 1.1093x over previous
//
#include <hip/hip_runtime.h>
#include <math.h>

typedef __attribute__((ext_vector_type(8))) short short8;
typedef __attribute__((ext_vector_type(4))) float f32x4;
typedef __attribute__((ext_vector_type(4))) unsigned short ushort4v;

#define D_MODEL 768
#define NH      12
#define DK      64
#define SEQ     1024
#define NB      8
#define MTOT    (NB*SEQ)                  // 8192
#define NELT    ((size_t)MTOT*D_MODEL)    // 6291456
#define WELT    ((size_t)D_MODEL*D_MODEL) // 589824
#define L2E     1.44269504088896f

__device__ __forceinline__ unsigned short f2bf(float f) {
    unsigned int u = __builtin_bit_cast(unsigned int, f);
    unsigned int r = (u + 0x7FFFu + ((u >> 16) & 1u)) >> 16;   // RNE
    return (unsigned short)r;
}
__device__ __forceinline__ float bf2f(unsigned short h) {
    return __builtin_bit_cast(float, ((unsigned int)h) << 16);
}
__device__ __forceinline__ void gload_lds16(const void* g, void* lds) {
    __builtin_amdgcn_global_load_lds(
        (const __attribute__((address_space(1))) unsigned int*)g,
        (__attribute__((address_space(3))) unsigned int*)lds, 16, 0, 0);
}

// ---------------------------------------------------------------------------
// fp32 -> bf16: q,k,v (3 x NELT) + wq,wk,wv,wo (4 x WELT) in one launch
// ---------------------------------------------------------------------------
__global__ __launch_bounds__(256) void cvt_all(
    const float* __restrict__ q, const float* __restrict__ k, const float* __restrict__ v,
    const float* __restrict__ wq, const float* __restrict__ wk,
    const float* __restrict__ wv, const float* __restrict__ wo,
    unsigned short* __restrict__ qb, unsigned short* __restrict__ kb, unsigned short* __restrict__ vb,
    unsigned short* __restrict__ wqb, unsigned short* __restrict__ wkb,
    unsigned short* __restrict__ wvb, unsigned short* __restrict__ wob)
{
    size_t i = (size_t)blockIdx.x * 256 + threadIdx.x;
    const size_t per = NELT / 8, wper = WELT / 8;
    const float* s; unsigned short* d; size_t l;
    if (i < per)            { s = q;  d = qb;  l = i; }
    else if (i < 2*per)     { s = k;  d = kb;  l = i - per; }
    else if (i < 3*per)     { s = v;  d = vb;  l = i - 2*per; }
    else {
        size_t j = i - 3*per;
        if (j < wper)        { s = wq; d = wqb; l = j; }
        else if (j < 2*wper) { s = wk; d = wkb; l = j - wper; }
        else if (j < 3*wper) { s = wv; d = wvb; l = j - 2*wper; }
        else                 { s = wo; d = wob; l = j - 3*wper; }
    }
    const float4* sp = (const float4*)(s + l*8);
    float4 v0 = sp[0], v1 = sp[1];
    short8 o;
    o[0]=(short)f2bf(v0.x); o[1]=(short)f2bf(v0.y); o[2]=(short)f2bf(v0.z); o[3]=(short)f2bf(v0.w);
    o[4]=(short)f2bf(v1.x); o[5]=(short)f2bf(v1.y); o[6]=(short)f2bf(v1.z); o[7]=(short)f2bf(v1.w);
    *(short8*)(d + l*8) = o;
}

// ---------------------------------------------------------------------------
// Merged projection GEMM (bf16 A via global_load_lds; z picks input).
// z = 0: Qp = (q@wq^T + bq)*0.125   (bf16 [8192][768])
// z = 1: Kp =  k@wk^T + bk          (bf16 [8192][768])
// z = 2: Vt = (v@wv^T + bv)^T       (bf16 [B,H,DK,SEQ])
// ---------------------------------------------------------------------------
#define BM 128
#define BN 128
#define BKG 64

__global__ __launch_bounds__(256) void proj_gemm(
    const unsigned short* __restrict__ Aq, const unsigned short* __restrict__ Ak,
    const unsigned short* __restrict__ Av,
    const unsigned short* __restrict__ Wq, const unsigned short* __restrict__ Wk,
    const unsigned short* __restrict__ Wv,
    const float* __restrict__ bq, const float* __restrict__ bk, const float* __restrict__ bv,
    unsigned short* __restrict__ Qp, unsigned short* __restrict__ Kp,
    unsigned short* __restrict__ Vtp)
{
    __shared__ unsigned short As[BM*BKG];
    __shared__ unsigned short Bs[BN*BKG];
    const int tid = threadIdx.x;
    const int lane = tid & 63, wid = tid >> 6;
    const int wr = wid >> 1, wc = wid & 1;
    const int m0 = blockIdx.y * BM, n0 = blockIdx.x * BN;
    const int z = blockIdx.z;

    const unsigned short* A = (z == 0) ? Aq : (z == 1) ? Ak : Av;
    const unsigned short* W = (z == 0) ? Wq : (z == 1) ? Wk : Wv;
    const float* bias       = (z == 0) ? bq : (z == 1) ? bk : bv;

    f32x4 acc[4][4];
    #pragma unroll
    for (int i = 0; i < 4; ++i)
        #pragma unroll
        for (int j = 0; j < 4; ++j) acc[i][j] = (f32x4)(0.f);

    for (int k0 = 0; k0 < D_MODEL; k0 += BKG) {
        __syncthreads();
        #pragma unroll
        for (int j = 0; j < 4; ++j) {
            int p = ((wid*4 + j) << 9) + lane*8;
            int row = p >> 6, off = p & 63;
            const unsigned short* srcA = A + (size_t)(m0+row)*D_MODEL + k0 + (off ^ ((row&7)<<3));
            gload_lds16(srcA, &As[(wid*4 + j) << 9]);
            const unsigned short* srcB = W + (size_t)(n0+row)*D_MODEL + k0 + (off ^ ((row&7)<<3));
            gload_lds16(srcB, &Bs[(wid*4 + j) << 9]);
        }
        __syncthreads();
        #pragma unroll
        for (int ks = 0; ks < 2; ++ks) {
            short8 af[4], bf8[4];
            #pragma unroll
            for (int mi = 0; mi < 4; ++mi) {
                int row = wr*64 + mi*16 + (lane & 15);
                af[mi] = *(const short8*)&As[row*BKG + ((ks*32 + (lane>>4)*8) ^ ((row&7)<<3))];
            }
            #pragma unroll
            for (int ni = 0; ni < 4; ++ni) {
                int row = wc*64 + ni*16 + (lane & 15);
                bf8[ni] = *(const short8*)&Bs[row*BKG + ((ks*32 + (lane>>4)*8) ^ ((row&7)<<3))];
            }
            #pragma unroll
            for (int mi = 0; mi < 4; ++mi)
                #pragma unroll
                for (int ni = 0; ni < 4; ++ni)
                    acc[mi][ni] = __builtin_amdgcn_mfma_f32_16x16x32_bf16(af[mi], bf8[ni], acc[mi][ni], 0, 0, 0);
        }
    }

    float bv4[4];
    #pragma unroll
    for (int ni = 0; ni < 4; ++ni) bv4[ni] = bias[n0 + wc*64 + ni*16 + (lane & 15)];

    if (z < 2) {
        unsigned short* C = (z == 0) ? Qp : Kp;
        const float scale = (z == 0) ? 0.125f : 1.0f;
        #pragma unroll
        for (int mi = 0; mi < 4; ++mi)
            #pragma unroll
            for (int ni = 0; ni < 4; ++ni) {
                int col = n0 + wc*64 + ni*16 + (lane & 15);
                int rbase = m0 + wr*64 + mi*16 + ((lane>>4)<<2);
                #pragma unroll
                for (int j = 0; j < 4; ++j)
                    C[(size_t)(rbase+j)*D_MODEL + col] = f2bf((acc[mi][ni][j] + bv4[ni]) * scale);
            }
    } else {
        #pragma unroll
        for (int mi = 0; mi < 4; ++mi)
            #pragma unroll
            for (int ni = 0; ni < 4; ++ni) {
                int col = n0 + wc*64 + ni*16 + (lane & 15);
                int hh = col >> 6, dd = col & 63;
                int m = m0 + wr*64 + mi*16 + ((lane>>4)<<2);
                int bb = m >> 10, ss = m & (SEQ-1);
                ushort4v pk;
                #pragma unroll
                for (int j = 0; j < 4; ++j) pk[j] = f2bf(acc[mi][ni][j] + bv4[ni]);
                *(ushort4v*)&Vtp[((size_t)(bb*NH + hh)*DK + dd)*SEQ + ss] = pk;
            }
    }
}

// ---------------------------------------------------------------------------
// Final GEMM: out_fp32 = Aop(bf16) @ wo^T + bo
// ---------------------------------------------------------------------------
__global__ __launch_bounds__(256) void gemm_out(
    const unsigned short* __restrict__ A, const unsigned short* __restrict__ W,
    const float* __restrict__ bias, float* __restrict__ C)
{
    __shared__ unsigned short As[BM*BKG];
    __shared__ unsigned short Bs[BN*BKG];
    const int tid = threadIdx.x;
    const int lane = tid & 63, wid = tid >> 6;
    const int wr = wid >> 1, wc = wid & 1;
    const int m0 = blockIdx.y * BM, n0 = blockIdx.x * BN;

    f32x4 acc[4][4];
    #pragma unroll
    for (int i = 0; i < 4; ++i)
        #pragma unroll
        for (int j = 0; j < 4; ++j) acc[i][j] = (f32x4)(0.f);

    for (int k0 = 0; k0 < D_MODEL; k0 += BKG) {
        __syncthreads();
        #pragma unroll
        for (int j = 0; j < 4; ++j) {
            int p = ((wid*4 + j) << 9) + lane*8;
            int row = p >> 6, off = p & 63;
            const unsigned short* srcA = A + (size_t)(m0+row)*D_MODEL + k0 + (off ^ ((row&7)<<3));
            gload_lds16(srcA, &As[(wid*4 + j) << 9]);
            const unsigned short* srcB = W + (size_t)(n0+row)*D_MODEL + k0 + (off ^ ((row&7)<<3));
            gload_lds16(srcB, &Bs[(wid*4 + j) << 9]);
        }
        __syncthreads();
        #pragma unroll
        for (int ks = 0; ks < 2; ++ks) {
            short8 af[4], bf8[4];
            #pragma unroll
            for (int mi = 0; mi < 4; ++mi) {
                int row = wr*64 + mi*16 + (lane & 15);
                af[mi] = *(const short8*)&As[row*BKG + ((ks*32 + (lane>>4)*8) ^ ((row&7)<<3))];
            }
            #pragma unroll
            for (int ni = 0; ni < 4; ++ni) {
                int row = wc*64 + ni*16 + (lane & 15);
                bf8[ni] = *(const short8*)&Bs[row*BKG + ((ks*32 + (lane>>4)*8) ^ ((row&7)<<3))];
            }
            #pragma unroll
            for (int mi = 0; mi < 4; ++mi)
                #pragma unroll
                for (int ni = 0; ni < 4; ++ni)
                    acc[mi][ni] = __builtin_amdgcn_mfma_f32_16x16x32_bf16(af[mi], bf8[ni], acc[mi][ni], 0, 0, 0);
        }
    }

    float bv4[4];
    #pragma unroll
    for (int ni = 0; ni < 4; ++ni) bv4[ni] = bias[n0 + wc*64 + ni*16 + (lane & 15)];

    #pragma unroll
    for (int mi = 0; mi < 4; ++mi)
        #pragma unroll
        for (int ni = 0; ni < 4; ++ni) {
            int col = n0 + wc*64 + ni*16 + (lane & 15);
            int rbase = m0 + wr*64 + mi*16 + ((lane>>4)<<2);
            #pragma unroll
            for (int j = 0; j < 4; ++j)
                C[(size_t)(rbase+j)*D_MODEL + col] = acc[mi][ni][j] + bv4[ni];
        }
}

// ---------------------------------------------------------------------------
// Flash attention — round-8 verified body (~60 us): conv folded into Q~
// (log2e pre-folded), swapped MFMA, online softmax in log2 domain with
// defer-rescale (THR=8). Scalar f2bf packing (no inline-asm cvt_pk).
// ---------------------------------------------------------------------------
#define KVB 64
#define NCH (SEQ/KVB)   // 16
#define THR 8.0f

__global__ __launch_bounds__(512, 4) void attn_flash(
    const unsigned short* __restrict__ Qp,   // [8192][768] bf16, scale folded
    const unsigned short* __restrict__ Kp,   // [8192][768] bf16
    const unsigned short* __restrict__ Vt,   // [96][64][1024] bf16
    const float* __restrict__ CW,
    unsigned short* __restrict__ Aop)        // [8192][768] bf16
{
    __shared__ unsigned short Ks[2][66*64];  // 16.5 KB (halo rows k-1..k+64)
    __shared__ unsigned short Vs[2][64*64];  // 16 KB  V^T chunk [64d][64k]
    __shared__ unsigned short UB[130*64];    // 16.25 KB: Qstage, then 8x2KB P

    const int tid = threadIdx.x;
    const int lane = tid & 63, wid = tid >> 6;
    const int lq = lane & 15, lg = lane >> 4;

    // XCD-aware bijective swizzle: 768 = 8 XCDs x 96
    const int bid = blockIdx.x;
    const int sw = (bid & 7) * 96 + (bid >> 3);
    const int q0 = (sw & 7) * 128;
    const int bh = sw >> 3;
    const int h = bh % NH, b = bh / NH;

    float wcv[9];
    #pragma unroll
    for (int i = 0; i < 9; ++i) wcv[i] = CW[h*9 + i];

    const unsigned short* KpB = Kp + (size_t)b*SEQ*D_MODEL + h*DK;
    const unsigned short* QpB = Qp + (size_t)b*SEQ*D_MODEL + h*DK;
    const char* VtB = (const char*)Vt + (size_t)bh*DK*SEQ*2;

    // ---- K chunk stage (66 rows = keys ck*64-1 .. ck*64+64), reg-staged ----
    short8 kr0, kr1;
    auto kload = [&](int ck) {
        { int r = tid >> 3, oct = tid & 7;
          int gk = ck*KVB - 1 + r;
          short8 v = (short8)0;
          if (gk >= 0 && gk < SEQ) v = *(const short8*)&KpB[(size_t)gk*D_MODEL + oct*8];
          kr0 = v; }
        if (tid < 16) {
          int r = 64 + (tid >> 3), oct = tid & 7;
          int gk = ck*KVB - 1 + r;
          short8 v = (short8)0;
          if (gk >= 0 && gk < SEQ) v = *(const short8*)&KpB[(size_t)gk*D_MODEL + oct*8];
          kr1 = v; }
    };
    auto kstore = [&](int buf) {
        { int r = tid >> 3, oct = tid & 7;
          *(short8*)&Ks[buf][r*64 + ((oct ^ (r&7)) << 3)] = kr0; }
        if (tid < 16) {
          int r = 64 + (tid >> 3), oct = tid & 7;
          *(short8*)&Ks[buf][r*64 + ((oct ^ (r&7)) << 3)] = kr1; }
    };
    // ---- V^T chunk stage via global_load_lds (linear dest, preswz src) ----
    auto vstage = [&](int ck, int buf) {
        int p = tid * 16;                 // byte pos in 8 KB
        int row = p >> 7, off = p & 127;  // 128 B per d-row (64 keys)
        const char* src = VtB + ((size_t)row*SEQ + ck*KVB)*2 + (off ^ ((row&7)<<4));
        gload_lds16(src, (char*)Vs[buf] + p);
    };

    kload(0);

    // ---- stage Q rows q0-1 .. q0+128 into UB (zero OOB) ----
    {
        short8 qs0 = (short8)0, qs1 = (short8)0, qs2 = (short8)0;
        int r0 = tid >> 3, o0 = tid & 7;
        int g0 = q0 - 1 + r0;
        if (g0 >= 0 && g0 < SEQ) qs0 = *(const short8*)&QpB[(size_t)g0*D_MODEL + o0*8];
        int r1 = (512 + tid) >> 3, o1 = tid & 7;
        int g1 = q0 - 1 + r1;
        if (g1 >= 0 && g1 < SEQ) qs1 = *(const short8*)&QpB[(size_t)g1*D_MODEL + o1*8];
        int r2 = 0, o2 = 0, g2 = -1;
        if (tid < 16) {
            r2 = (1024 + tid) >> 3; o2 = tid & 7;
            g2 = q0 - 1 + r2;
            if (g2 >= 0 && g2 < SEQ) qs2 = *(const short8*)&QpB[(size_t)g2*D_MODEL + o2*8];
        }
        *(short8*)&UB[r0*64 + ((o0 ^ (r0&7)) << 3)] = qs0;
        *(short8*)&UB[r1*64 + ((o1 ^ (r1&7)) << 3)] = qs1;
        if (tid < 16) *(short8*)&UB[r2*64 + ((o2 ^ (r2&7)) << 3)] = qs2;
    }
    __syncthreads();

    // ---- build Q~ B-frags (x log2e): q = lane&15, d-octs ks*32+lg*8 ----
    short8 qtf0[2], qtf1[2], qtf2[2];
    {
        int r0 = wid*16 + lq;     // Qstage row of Q[q-1]
        #pragma unroll
        for (int ks = 0; ks < 2; ++ks) {
            int oct = ks*4 + lg;
            int ra = r0, rb = r0 + 1, rc = r0 + 2;
            short8 am = *(const short8*)&UB[ra*64 + ((oct ^ (ra&7)) << 3)];
            short8 ac = *(const short8*)&UB[rb*64 + ((oct ^ (rb&7)) << 3)];
            short8 ap = *(const short8*)&UB[rc*64 + ((oct ^ (rc&7)) << 3)];
            short8 f0, f1, f2;
            #pragma unroll
            for (int j = 0; j < 8; ++j) {
                float fm = bf2f((unsigned short)am[j]);
                float fc = bf2f((unsigned short)ac[j]);
                float fp = bf2f((unsigned short)ap[j]);
                float t0 = (fc - (wcv[1]*fm + wcv[4]*fc + wcv[7]*fp)) * L2E;
                float t1 = -(wcv[0]*fm + wcv[3]*fc + wcv[6]*fp) * L2E;
                float t2 = -(wcv[2]*fm + wcv[5]*fc + wcv[8]*fp) * L2E;
                f0[j] = (short)f2bf(t0);
                f1[j] = (short)f2bf(t1);
                f2[j] = (short)f2bf(t2);
            }
            qtf0[ks] = f0; qtf1[ks] = f1; qtf2[ks] = f2;
        }
    }
    kstore(0);
    vstage(0, 0);
    __syncthreads();

    unsigned short* Pw = &UB[wid * 1024];   // per-warp [16 q][64 k]

    float m = -1e30f, l = 0.f;
    f32x4 oac[4];
    #pragma unroll
    for (int dt = 0; dt < 4; ++dt) oac[dt] = (f32x4)(0.f);

    int cur = 0;
    for (int ck = 0; ck < NCH; ++ck) {
        if (ck < NCH-1) { kload(ck+1); vstage(ck+1, cur^1); }

        // ---- QK~^T: 4 k-tiles of 16; slot pairing K[k+{0,-1,+1}] via halo ----
        f32x4 st[4];
        #pragma unroll
        for (int t = 0; t < 4; ++t) {
            f32x4 s = (f32x4)(0.f);
            #pragma unroll
            for (int ks = 0; ks < 2; ++ks) {
                int oct = ks*4 + lg;
                int ar0 = t*16 + lq + 1;   // slot0 (Q-D1) -> K[k]
                short8 a0 = *(const short8*)&Ks[cur][ar0*64 + ((oct ^ (ar0&7)) << 3)];
                s = __builtin_amdgcn_mfma_f32_16x16x32_bf16(a0, qtf0[ks], s, 0, 0, 0);
                int ar1 = t*16 + lq;       // slot1 (-D0) -> K[k-1]
                short8 a1 = *(const short8*)&Ks[cur][ar1*64 + ((oct ^ (ar1&7)) << 3)];
                s = __builtin_amdgcn_mfma_f32_16x16x32_bf16(a1, qtf1[ks], s, 0, 0, 0);
                int ar2 = t*16 + lq + 2;   // slot2 (-D2) -> K[k+1]
                short8 a2 = *(const short8*)&Ks[cur][ar2*64 + ((oct ^ (ar2&7)) << 3)];
                s = __builtin_amdgcn_mfma_f32_16x16x32_bf16(a2, qtf2[ks], s, 0, 0, 0);
            }
            st[t] = s;
        }

        // ---- online softmax, log2 domain, defer-rescale (THR) ----
        float tmax = -1e30f;
        #pragma unroll
        for (int t = 0; t < 4; ++t)
            #pragma unroll
            for (int j = 0; j < 4; ++j) tmax = fmaxf(tmax, st[t][j]);
        tmax = fmaxf(tmax, __shfl_xor(tmax, 16));
        tmax = fmaxf(tmax, __shfl_xor(tmax, 32));

        if (!__all(tmax - m <= THR)) {
            float mn = fmaxf(m, tmax);
            float r = exp2f(m - mn);
            l *= r;
            #pragma unroll
            for (int dt = 0; dt < 4; ++dt)
                #pragma unroll
                for (int j = 0; j < 4; ++j) oac[dt][j] *= r;
            m = mn;
        }
        float lsum = 0.f;
        #pragma unroll
        for (int t = 0; t < 4; ++t)
            #pragma unroll
            for (int j = 0; j < 4; ++j) {
                float e = exp2f(st[t][j] - m);
                st[t][j] = e;
                lsum += e;
            }
        lsum += __shfl_xor(lsum, 16);
        lsum += __shfl_xor(lsum, 32);
        l += lsum;

        // ---- P -> per-warp LDS (k-consecutive packs), then PV ----
        #pragma unroll
        for (int t = 0; t < 4; ++t) {
            ushort4v pk;
            #pragma unroll
            for (int j = 0; j < 4; ++j) pk[j] = f2bf(st[t][j]);
            *(ushort4v*)&Pw[lq*64 + ((t*16 + lg*4) ^ ((lq&7)<<3))] = pk;
        }
        #pragma unroll
        for (int kk = 0; kk < 2; ++kk) {
            short8 p8 = *(const short8*)&Pw[lq*64 + ((kk*32 + lg*8) ^ ((lq&7)<<3))];
            #pragma unroll
            for (int dt = 0; dt < 4; ++dt) {
                int vr = dt*16 + lq;
                int voct = kk*4 + lg;
                short8 v8 = *(const short8*)&Vs[cur][vr*64 + ((voct ^ (vr&7)) << 3)];
                oac[dt] = __builtin_amdgcn_mfma_f32_16x16x32_bf16(v8, p8, oac[dt], 0, 0, 0);
            }
        }

        if (ck < NCH-1) kstore(cur^1);
        __syncthreads();
        cur ^= 1;
    }

    // ---- epilogue: O^T col = q = lane&15; divide by l; write 4x8B ----
    float invl = 1.0f / l;
    int qg = q0 + wid*16 + lq;
    #pragma unroll
    for (int dt = 0; dt < 4; ++dt) {
        ushort4v o;
        #pragma unroll
        for (int j = 0; j < 4; ++j) o[j] = f2bf(oac[dt][j] * invl);
        *(ushort4v*)&Aop[(size_t)(b*SEQ + qg)*D_MODEL + h*DK + dt*16 + lg*4] = o;
    }
}

// ---------------------------------------------------------------------------
extern "C" void kernel_launch(void* const* d_in, const int* in_sizes, int n_in,
                              void* d_out, int out_size, void* d_ws, size_t ws_size,
                              hipStream_t stream)
{
    const float* q  = (const float*)d_in[0];
    const float* k  = (const float*)d_in[1];
    const float* v  = (const float*)d_in[2];
    const float* wq = (const float*)d_in[3];
    const float* bq = (const float*)d_in[4];
    const float* wk = (const float*)d_in[5];
    const float* bk = (const float*)d_in[6];
    const float* wv = (const float*)d_in[7];
    const float* bv = (const float*)d_in[8];
    const float* wo = (const float*)d_in[9];
    const float* bo = (const float*)d_in[10];
    const float* cw = (const float*)d_in[11];

    unsigned short* qb  = (unsigned short*)d_ws;
    unsigned short* kb  = qb  + NELT;
    unsigned short* vb  = kb  + NELT;
    unsigned short* wqb = vb  + NELT;
    unsigned short* wkb = wqb + WELT;
    unsigned short* wvb = wkb + WELT;
    unsigned short* wob = wvb + WELT;
    unsigned short* Qp  = wob + WELT;
    unsigned short* Kp  = Qp  + NELT;
    unsigned short* Vtp = Kp  + NELT;
    unsigned short* Aop = Vtp + NELT;

    const int cvtBlocks = (int)((3*NELT + 4*WELT) / 8 / 256);
    cvt_all<<<cvtBlocks, 256, 0, stream>>>(q, k, v, wq, wk, wv, wo,
                                           qb, kb, vb, wqb, wkb, wvb, wob);

    dim3 gg(D_MODEL/BN, MTOT/BM, 3);   // (6, 64, 3) = 1152 blocks
    proj_gemm<<<gg, 256, 0, stream>>>(qb, kb, vb, wqb, wkb, wvb, bq, bk, bv, Qp, Kp, Vtp);

    attn_flash<<<dim3(768), 512, 0, stream>>>(Qp, Kp, Vtp, cw, Aop);

    gemm_out<<<dim3(D_MODEL/BN, MTOT/BM), 256, 0, stream>>>(Aop, wob, bo, (float*)d_out);
}

// Round 12
// 163.204 us; speedup vs baseline: 1.1703x; 1.0550x over previous
//
#include <hip/hip_runtime.h>
#include <math.h>

typedef __attribute__((ext_vector_type(8))) short short8;
typedef __attribute__((ext_vector_type(4))) float f32x4;
typedef __attribute__((ext_vector_type(4))) unsigned short ushort4v;

#define D_MODEL 768
#define NH      12
#define DK      64
#define SEQ     1024
#define NB      8
#define MTOT    (NB*SEQ)                  // 8192
#define NELT    ((size_t)MTOT*D_MODEL)    // 6291456
#define WELT    ((size_t)D_MODEL*D_MODEL) // 589824
#define L2E     1.44269504088896f

__device__ __forceinline__ unsigned short f2bf(float f) {
    unsigned int u = __builtin_bit_cast(unsigned int, f);
    unsigned int r = (u + 0x7FFFu + ((u >> 16) & 1u)) >> 16;   // RNE
    return (unsigned short)r;
}
__device__ __forceinline__ float bf2f(unsigned short h) {
    return __builtin_bit_cast(float, ((unsigned int)h) << 16);
}
__device__ __forceinline__ float fast_exp2(float x) {
#if __has_builtin(__builtin_amdgcn_exp2f)
    return __builtin_amdgcn_exp2f(x);        // bare v_exp_f32
#else
    return __expf(x * 0.69314718056f);
#endif
}
// pack two floats -> two bf16 (round-nearest) in one u32: {hi.bf16, lo.bf16}
__device__ __forceinline__ unsigned int pk_bf16_rn(float lo, float hi) {
    unsigned int ul = __builtin_bit_cast(unsigned int, lo) + 0x8000u;
    unsigned int uh = __builtin_bit_cast(unsigned int, hi) + 0x8000u;
    return __builtin_amdgcn_perm(uh, ul, 0x07060302u);  // {uh[3:2], ul[3:2]}
}
__device__ __forceinline__ void gload_lds16(const void* g, void* lds) {
    __builtin_amdgcn_global_load_lds(
        (const __attribute__((address_space(1))) unsigned int*)g,
        (__attribute__((address_space(3))) unsigned int*)lds, 16, 0, 0);
}

// ---------------------------------------------------------------------------
// fp32 -> bf16: q,k,v (3 x NELT) + wq,wk,wv,wo (4 x WELT) in one launch
// ---------------------------------------------------------------------------
__global__ __launch_bounds__(256) void cvt_all(
    const float* __restrict__ q, const float* __restrict__ k, const float* __restrict__ v,
    const float* __restrict__ wq, const float* __restrict__ wk,
    const float* __restrict__ wv, const float* __restrict__ wo,
    unsigned short* __restrict__ qb, unsigned short* __restrict__ kb, unsigned short* __restrict__ vb,
    unsigned short* __restrict__ wqb, unsigned short* __restrict__ wkb,
    unsigned short* __restrict__ wvb, unsigned short* __restrict__ wob)
{
    size_t i = (size_t)blockIdx.x * 256 + threadIdx.x;
    const size_t per = NELT / 8, wper = WELT / 8;
    const float* s; unsigned short* d; size_t l;
    if (i < per)            { s = q;  d = qb;  l = i; }
    else if (i < 2*per)     { s = k;  d = kb;  l = i - per; }
    else if (i < 3*per)     { s = v;  d = vb;  l = i - 2*per; }
    else {
        size_t j = i - 3*per;
        if (j < wper)        { s = wq; d = wqb; l = j; }
        else if (j < 2*wper) { s = wk; d = wkb; l = j - wper; }
        else if (j < 3*wper) { s = wv; d = wvb; l = j - 2*wper; }
        else                 { s = wo; d = wob; l = j - 3*wper; }
    }
    const float4* sp = (const float4*)(s + l*8);
    float4 v0 = sp[0], v1 = sp[1];
    short8 o;
    o[0]=(short)f2bf(v0.x); o[1]=(short)f2bf(v0.y); o[2]=(short)f2bf(v0.z); o[3]=(short)f2bf(v0.w);
    o[4]=(short)f2bf(v1.x); o[5]=(short)f2bf(v1.y); o[6]=(short)f2bf(v1.z); o[7]=(short)f2bf(v1.w);
    *(short8*)(d + l*8) = o;
}

// ---------------------------------------------------------------------------
// Merged projection GEMM (bf16 A via global_load_lds; z picks input).
// z = 0: Qp = (q@wq^T + bq)*0.125   (bf16 [8192][768])
// z = 1: Kp =  k@wk^T + bk          (bf16 [8192][768])
// z = 2: Vt = (v@wv^T + bv)^T       (bf16 [B,H,DK,SEQ])
// ---------------------------------------------------------------------------
#define BM 128
#define BN 128
#define BKG 64

__global__ __launch_bounds__(256) void proj_gemm(
    const unsigned short* __restrict__ Aq, const unsigned short* __restrict__ Ak,
    const unsigned short* __restrict__ Av,
    const unsigned short* __restrict__ Wq, const unsigned short* __restrict__ Wk,
    const unsigned short* __restrict__ Wv,
    const float* __restrict__ bq, const float* __restrict__ bk, const float* __restrict__ bv,
    unsigned short* __restrict__ Qp, unsigned short* __restrict__ Kp,
    unsigned short* __restrict__ Vtp)
{
    __shared__ unsigned short As[BM*BKG];
    __shared__ unsigned short Bs[BN*BKG];
    const int tid = threadIdx.x;
    const int lane = tid & 63, wid = tid >> 6;
    const int wr = wid >> 1, wc = wid & 1;
    const int m0 = blockIdx.y * BM, n0 = blockIdx.x * BN;
    const int z = blockIdx.z;

    const unsigned short* A = (z == 0) ? Aq : (z == 1) ? Ak : Av;
    const unsigned short* W = (z == 0) ? Wq : (z == 1) ? Wk : Wv;
    const float* bias       = (z == 0) ? bq : (z == 1) ? bk : bv;

    f32x4 acc[4][4];
    #pragma unroll
    for (int i = 0; i < 4; ++i)
        #pragma unroll
        for (int j = 0; j < 4; ++j) acc[i][j] = (f32x4)(0.f);

    for (int k0 = 0; k0 < D_MODEL; k0 += BKG) {
        __syncthreads();
        #pragma unroll
        for (int j = 0; j < 4; ++j) {
            int p = ((wid*4 + j) << 9) + lane*8;
            int row = p >> 6, off = p & 63;
            const unsigned short* srcA = A + (size_t)(m0+row)*D_MODEL + k0 + (off ^ ((row&7)<<3));
            gload_lds16(srcA, &As[(wid*4 + j) << 9]);
            const unsigned short* srcB = W + (size_t)(n0+row)*D_MODEL + k0 + (off ^ ((row&7)<<3));
            gload_lds16(srcB, &Bs[(wid*4 + j) << 9]);
        }
        __syncthreads();
        #pragma unroll
        for (int ks = 0; ks < 2; ++ks) {
            short8 af[4], bf8[4];
            #pragma unroll
            for (int mi = 0; mi < 4; ++mi) {
                int row = wr*64 + mi*16 + (lane & 15);
                af[mi] = *(const short8*)&As[row*BKG + ((ks*32 + (lane>>4)*8) ^ ((row&7)<<3))];
            }
            #pragma unroll
            for (int ni = 0; ni < 4; ++ni) {
                int row = wc*64 + ni*16 + (lane & 15);
                bf8[ni] = *(const short8*)&Bs[row*BKG + ((ks*32 + (lane>>4)*8) ^ ((row&7)<<3))];
            }
            #pragma unroll
            for (int mi = 0; mi < 4; ++mi)
                #pragma unroll
                for (int ni = 0; ni < 4; ++ni)
                    acc[mi][ni] = __builtin_amdgcn_mfma_f32_16x16x32_bf16(af[mi], bf8[ni], acc[mi][ni], 0, 0, 0);
        }
    }

    float bv4[4];
    #pragma unroll
    for (int ni = 0; ni < 4; ++ni) bv4[ni] = bias[n0 + wc*64 + ni*16 + (lane & 15)];

    if (z < 2) {
        unsigned short* C = (z == 0) ? Qp : Kp;
        const float scale = (z == 0) ? 0.125f : 1.0f;
        #pragma unroll
        for (int mi = 0; mi < 4; ++mi)
            #pragma unroll
            for (int ni = 0; ni < 4; ++ni) {
                int col = n0 + wc*64 + ni*16 + (lane & 15);
                int rbase = m0 + wr*64 + mi*16 + ((lane>>4)<<2);
                #pragma unroll
                for (int j = 0; j < 4; ++j)
                    C[(size_t)(rbase+j)*D_MODEL + col] = f2bf((acc[mi][ni][j] + bv4[ni]) * scale);
            }
    } else {
        #pragma unroll
        for (int mi = 0; mi < 4; ++mi)
            #pragma unroll
            for (int ni = 0; ni < 4; ++ni) {
                int col = n0 + wc*64 + ni*16 + (lane & 15);
                int hh = col >> 6, dd = col & 63;
                int m = m0 + wr*64 + mi*16 + ((lane>>4)<<2);
                int bb = m >> 10, ss = m & (SEQ-1);
                ushort4v pk;
                #pragma unroll
                for (int j = 0; j < 4; ++j) pk[j] = f2bf(acc[mi][ni][j] + bv4[ni]);
                *(ushort4v*)&Vtp[((size_t)(bb*NH + hh)*DK + dd)*SEQ + ss] = pk;
            }
    }
}

// ---------------------------------------------------------------------------
// Final GEMM: out_fp32 = Aop(bf16) @ wo^T + bo
// ---------------------------------------------------------------------------
__global__ __launch_bounds__(256) void gemm_out(
    const unsigned short* __restrict__ A, const unsigned short* __restrict__ W,
    const float* __restrict__ bias, float* __restrict__ C)
{
    __shared__ unsigned short As[BM*BKG];
    __shared__ unsigned short Bs[BN*BKG];
    const int tid = threadIdx.x;
    const int lane = tid & 63, wid = tid >> 6;
    const int wr = wid >> 1, wc = wid & 1;
    const int m0 = blockIdx.y * BM, n0 = blockIdx.x * BN;

    f32x4 acc[4][4];
    #pragma unroll
    for (int i = 0; i < 4; ++i)
        #pragma unroll
        for (int j = 0; j < 4; ++j) acc[i][j] = (f32x4)(0.f);

    for (int k0 = 0; k0 < D_MODEL; k0 += BKG) {
        __syncthreads();
        #pragma unroll
        for (int j = 0; j < 4; ++j) {
            int p = ((wid*4 + j) << 9) + lane*8;
            int row = p >> 6, off = p & 63;
            const unsigned short* srcA = A + (size_t)(m0+row)*D_MODEL + k0 + (off ^ ((row&7)<<3));
            gload_lds16(srcA, &As[(wid*4 + j) << 9]);
            const unsigned short* srcB = W + (size_t)(n0+row)*D_MODEL + k0 + (off ^ ((row&7)<<3));
            gload_lds16(srcB, &Bs[(wid*4 + j) << 9]);
        }
        __syncthreads();
        #pragma unroll
        for (int ks = 0; ks < 2; ++ks) {
            short8 af[4], bf8[4];
            #pragma unroll
            for (int mi = 0; mi < 4; ++mi) {
                int row = wr*64 + mi*16 + (lane & 15);
                af[mi] = *(const short8*)&As[row*BKG + ((ks*32 + (lane>>4)*8) ^ ((row&7)<<3))];
            }
            #pragma unroll
            for (int ni = 0; ni < 4; ++ni) {
                int row = wc*64 + ni*16 + (lane & 15);
                bf8[ni] = *(const short8*)&Bs[row*BKG + ((ks*32 + (lane>>4)*8) ^ ((row&7)<<3))];
            }
            #pragma unroll
            for (int mi = 0; mi < 4; ++mi)
                #pragma unroll
                for (int ni = 0; ni < 4; ++ni)
                    acc[mi][ni] = __builtin_amdgcn_mfma_f32_16x16x32_bf16(af[mi], bf8[ni], acc[mi][ni], 0, 0, 0);
        }
    }

    float bv4[4];
    #pragma unroll
    for (int ni = 0; ni < 4; ++ni) bv4[ni] = bias[n0 + wc*64 + ni*16 + (lane & 15)];

    #pragma unroll
    for (int mi = 0; mi < 4; ++mi)
        #pragma unroll
        for (int ni = 0; ni < 4; ++ni) {
            int col = n0 + wc*64 + ni*16 + (lane & 15);
            int rbase = m0 + wr*64 + mi*16 + ((lane>>4)<<2);
            #pragma unroll
            for (int j = 0; j < 4; ++j)
                C[(size_t)(rbase+j)*D_MODEL + col] = acc[mi][ni][j] + bv4[ni];
        }
}

// ---------------------------------------------------------------------------
// Flash attention: conv folded into Q~ (log2e pre-folded), swapped MFMA,
// online softmax in log2 domain, defer-rescale (THR=8), fast v_exp_f32,
// P-pack via add + v_perm_b32 (round-nearest).
// ---------------------------------------------------------------------------
#define KVB 64
#define NCH (SEQ/KVB)   // 16
#define THR 8.0f

__global__ __launch_bounds__(512, 4) void attn_flash(
    const unsigned short* __restrict__ Qp,   // [8192][768] bf16, scale folded
    const unsigned short* __restrict__ Kp,   // [8192][768] bf16
    const unsigned short* __restrict__ Vt,   // [96][64][1024] bf16
    const float* __restrict__ CW,
    unsigned short* __restrict__ Aop)        // [8192][768] bf16
{
    __shared__ unsigned short Ks[2][66*64];  // 16.5 KB (halo rows k-1..k+64)
    __shared__ unsigned short Vs[2][64*64];  // 16 KB  V^T chunk [64d][64k]
    __shared__ unsigned short UB[130*64];    // 16.25 KB: Qstage, then 8x2KB P

    const int tid = threadIdx.x;
    const int lane = tid & 63, wid = tid >> 6;
    const int lq = lane & 15, lg = lane >> 4;

    // XCD-aware bijective swizzle: 768 = 8 XCDs x 96
    const int bid = blockIdx.x;
    const int sw = (bid & 7) * 96 + (bid >> 3);
    const int q0 = (sw & 7) * 128;
    const int bh = sw >> 3;
    const int h = bh % NH, b = bh / NH;

    float wcv[9];
    #pragma unroll
    for (int i = 0; i < 9; ++i) wcv[i] = CW[h*9 + i];

    const unsigned short* KpB = Kp + (size_t)b*SEQ*D_MODEL + h*DK;
    const unsigned short* QpB = Qp + (size_t)b*SEQ*D_MODEL + h*DK;
    const char* VtB = (const char*)Vt + (size_t)bh*DK*SEQ*2;

    // ---- K chunk stage (66 rows = keys ck*64-1 .. ck*64+64), reg-staged ----
    short8 kr0, kr1;
    auto kload = [&](int ck) {
        { int r = tid >> 3, oct = tid & 7;
          int gk = ck*KVB - 1 + r;
          short8 v = (short8)0;
          if (gk >= 0 && gk < SEQ) v = *(const short8*)&KpB[(size_t)gk*D_MODEL + oct*8];
          kr0 = v; }
        if (tid < 16) {
          int r = 64 + (tid >> 3), oct = tid & 7;
          int gk = ck*KVB - 1 + r;
          short8 v = (short8)0;
          if (gk >= 0 && gk < SEQ) v = *(const short8*)&KpB[(size_t)gk*D_MODEL + oct*8];
          kr1 = v; }
    };
    auto kstore = [&](int buf) {
        { int r = tid >> 3, oct = tid & 7;
          *(short8*)&Ks[buf][r*64 + ((oct ^ (r&7)) << 3)] = kr0; }
        if (tid < 16) {
          int r = 64 + (tid >> 3), oct = tid & 7;
          *(short8*)&Ks[buf][r*64 + ((oct ^ (r&7)) << 3)] = kr1; }
    };
    // ---- V^T chunk stage via global_load_lds (linear dest, preswz src) ----
    auto vstage = [&](int ck, int buf) {
        int p = tid * 16;                 // byte pos in 8 KB
        int row = p >> 7, off = p & 127;  // 128 B per d-row (64 keys)
        const char* src = VtB + ((size_t)row*SEQ + ck*KVB)*2 + (off ^ ((row&7)<<4));
        gload_lds16(src, (char*)Vs[buf] + p);
    };

    kload(0);

    // ---- stage Q rows q0-1 .. q0+128 into UB (zero OOB) ----
    {
        short8 qs0 = (short8)0, qs1 = (short8)0, qs2 = (short8)0;
        int r0 = tid >> 3, o0 = tid & 7;
        int g0 = q0 - 1 + r0;
        if (g0 >= 0 && g0 < SEQ) qs0 = *(const short8*)&QpB[(size_t)g0*D_MODEL + o0*8];
        int r1 = (512 + tid) >> 3, o1 = tid & 7;
        int g1 = q0 - 1 + r1;
        if (g1 >= 0 && g1 < SEQ) qs1 = *(const short8*)&QpB[(size_t)g1*D_MODEL + o1*8];
        int r2 = 0, o2 = 0, g2 = -1;
        if (tid < 16) {
            r2 = (1024 + tid) >> 3; o2 = tid & 7;
            g2 = q0 - 1 + r2;
            if (g2 >= 0 && g2 < SEQ) qs2 = *(const short8*)&QpB[(size_t)g2*D_MODEL + o2*8];
        }
        *(short8*)&UB[r0*64 + ((o0 ^ (r0&7)) << 3)] = qs0;
        *(short8*)&UB[r1*64 + ((o1 ^ (r1&7)) << 3)] = qs1;
        if (tid < 16) *(short8*)&UB[r2*64 + ((o2 ^ (r2&7)) << 3)] = qs2;
    }
    __syncthreads();

    // ---- build Q~ B-frags (x log2e): q = lane&15, d-octs ks*32+lg*8 ----
    short8 qtf0[2], qtf1[2], qtf2[2];
    {
        int r0 = wid*16 + lq;     // Qstage row of Q[q-1]
        #pragma unroll
        for (int ks = 0; ks < 2; ++ks) {
            int oct = ks*4 + lg;
            int ra = r0, rb = r0 + 1, rc = r0 + 2;
            short8 am = *(const short8*)&UB[ra*64 + ((oct ^ (ra&7)) << 3)];
            short8 ac = *(const short8*)&UB[rb*64 + ((oct ^ (rb&7)) << 3)];
            short8 ap = *(const short8*)&UB[rc*64 + ((oct ^ (rc&7)) << 3)];
            short8 f0, f1, f2;
            #pragma unroll
            for (int j = 0; j < 8; ++j) {
                float fm = bf2f((unsigned short)am[j]);
                float fc = bf2f((unsigned short)ac[j]);
                float fp = bf2f((unsigned short)ap[j]);
                float t0 = (fc - (wcv[1]*fm + wcv[4]*fc + wcv[7]*fp)) * L2E;
                float t1 = -(wcv[0]*fm + wcv[3]*fc + wcv[6]*fp) * L2E;
                float t2 = -(wcv[2]*fm + wcv[5]*fc + wcv[8]*fp) * L2E;
                f0[j] = (short)f2bf(t0);
                f1[j] = (short)f2bf(t1);
                f2[j] = (short)f2bf(t2);
            }
            qtf0[ks] = f0; qtf1[ks] = f1; qtf2[ks] = f2;
        }
    }
    kstore(0);
    vstage(0, 0);
    __syncthreads();

    unsigned short* Pw = &UB[wid * 1024];   // per-warp [16 q][64 k]

    float m = -1e30f, l = 0.f;
    f32x4 oac[4];
    #pragma unroll
    for (int dt = 0; dt < 4; ++dt) oac[dt] = (f32x4)(0.f);

    int cur = 0;
    for (int ck = 0; ck < NCH; ++ck) {
        if (ck < NCH-1) { kload(ck+1); vstage(ck+1, cur^1); }

        // ---- QK~^T: 4 k-tiles of 16; slot pairing K[k+{0,-1,+1}] via halo ----
        f32x4 st[4];
        #pragma unroll
        for (int t = 0; t < 4; ++t) {
            f32x4 s = (f32x4)(0.f);
            #pragma unroll
            for (int ks = 0; ks < 2; ++ks) {
                int oct = ks*4 + lg;
                int ar0 = t*16 + lq + 1;   // slot0 (Q-D1) -> K[k]
                short8 a0 = *(const short8*)&Ks[cur][ar0*64 + ((oct ^ (ar0&7)) << 3)];
                s = __builtin_amdgcn_mfma_f32_16x16x32_bf16(a0, qtf0[ks], s, 0, 0, 0);
                int ar1 = t*16 + lq;       // slot1 (-D0) -> K[k-1]
                short8 a1 = *(const short8*)&Ks[cur][ar1*64 + ((oct ^ (ar1&7)) << 3)];
                s = __builtin_amdgcn_mfma_f32_16x16x32_bf16(a1, qtf1[ks], s, 0, 0, 0);
                int ar2 = t*16 + lq + 2;   // slot2 (-D2) -> K[k+1]
                short8 a2 = *(const short8*)&Ks[cur][ar2*64 + ((oct ^ (ar2&7)) << 3)];
                s = __builtin_amdgcn_mfma_f32_16x16x32_bf16(a2, qtf2[ks], s, 0, 0, 0);
            }
            st[t] = s;
        }

        // ---- online softmax, log2 domain, defer-rescale (THR) ----
        float tmax = -1e30f;
        #pragma unroll
        for (int t = 0; t < 4; ++t)
            #pragma unroll
            for (int j = 0; j < 4; ++j) tmax = fmaxf(tmax, st[t][j]);
        tmax = fmaxf(tmax, __shfl_xor(tmax, 16));
        tmax = fmaxf(tmax, __shfl_xor(tmax, 32));

        if (!__all(tmax - m <= THR)) {
            float mn = fmaxf(m, tmax);
            float r = fast_exp2(m - mn);
            l *= r;
            #pragma unroll
            for (int dt = 0; dt < 4; ++dt)
                #pragma unroll
                for (int j = 0; j < 4; ++j) oac[dt][j] *= r;
            m = mn;
        }
        float lsum = 0.f;
        #pragma unroll
        for (int t = 0; t < 4; ++t)
            #pragma unroll
            for (int j = 0; j < 4; ++j) {
                float e = fast_exp2(st[t][j] - m);
                st[t][j] = e;
                lsum += e;
            }
        lsum += __shfl_xor(lsum, 16);
        lsum += __shfl_xor(lsum, 32);
        l += lsum;

        // ---- P -> per-warp LDS (add+perm pack), then PV ----
        #pragma unroll
        for (int t = 0; t < 4; ++t) {
            uint2 pk;
            pk.x = pk_bf16_rn(st[t][0], st[t][1]);
            pk.y = pk_bf16_rn(st[t][2], st[t][3]);
            *(uint2*)&Pw[lq*64 + ((t*16 + lg*4) ^ ((lq&7)<<3))] = pk;
        }
        #pragma unroll
        for (int kk = 0; kk < 2; ++kk) {
            short8 p8 = *(const short8*)&Pw[lq*64 + ((kk*32 + lg*8) ^ ((lq&7)<<3))];
            #pragma unroll
            for (int dt = 0; dt < 4; ++dt) {
                int vr = dt*16 + lq;
                int voct = kk*4 + lg;
                short8 v8 = *(const short8*)&Vs[cur][vr*64 + ((voct ^ (vr&7)) << 3)];
                oac[dt] = __builtin_amdgcn_mfma_f32_16x16x32_bf16(v8, p8, oac[dt], 0, 0, 0);
            }
        }

        if (ck < NCH-1) kstore(cur^1);
        __syncthreads();
        cur ^= 1;
    }

    // ---- epilogue: O^T col = q = lane&15; divide by l; write 4x8B ----
    float invl = 1.0f / l;
    int qg = q0 + wid*16 + lq;
    #pragma unroll
    for (int dt = 0; dt < 4; ++dt) {
        uint2 o;
        o.x = pk_bf16_rn(oac[dt][0] * invl, oac[dt][1] * invl);
        o.y = pk_bf16_rn(oac[dt][2] * invl, oac[dt][3] * invl);
        *(uint2*)&Aop[(size_t)(b*SEQ + qg)*D_MODEL + h*DK + dt*16 + lg*4] = o;
    }
}

// ---------------------------------------------------------------------------
extern "C" void kernel_launch(void* const* d_in, const int* in_sizes, int n_in,
                              void* d_out, int out_size, void* d_ws, size_t ws_size,
                              hipStream_t stream)
{
    const float* q  = (const float*)d_in[0];
    const float* k  = (const float*)d_in[1];
    const float* v  = (const float*)d_in[2];
    const float* wq = (const float*)d_in[3];
    const float* bq = (const float*)d_in[4];
    const float* wk = (const float*)d_in[5];
    const float* bk = (const float*)d_in[6];
    const float* wv = (const float*)d_in[7];
    const float* bv = (const float*)d_in[8];
    const float* wo = (const float*)d_in[9];
    const float* bo = (const float*)d_in[10];
    const float* cw = (const float*)d_in[11];

    unsigned short* qb  = (unsigned short*)d_ws;
    unsigned short* kb  = qb  + NELT;
    unsigned short* vb  = kb  + NELT;
    unsigned short* wqb = vb  + NELT;
    unsigned short* wkb = wqb + WELT;
    unsigned short* wvb = wkb + WELT;
    unsigned short* wob = wvb + WELT;
    unsigned short* Qp  = wob + WELT;
    unsigned short* Kp  = Qp  + NELT;
    unsigned short* Vtp = Kp  + NELT;
    unsigned short* Aop = Vtp + NELT;

    const int cvtBlocks = (int)((3*NELT + 4*WELT) / 8 / 256);
    cvt_all<<<cvtBlocks, 256, 0, stream>>>(q, k, v, wq, wk, wv, wo,
                                           qb, kb, vb, wqb, wkb, wvb, wob);

    dim3 gg(D_MODEL/BN, MTOT/BM, 3);   // (6, 64, 3) = 1152 blocks
    proj_gemm<<<gg, 256, 0, stream>>>(qb, kb, vb, wqb, wkb, wvb, bq, bk, bv, Qp, Kp, Vtp);

    attn_flash<<<dim3(768), 512, 0, stream>>>(Qp, Kp, Vtp, cw, Aop);

    gemm_out<<<dim3(D_MODEL/BN, MTOT/BM), 256, 0, stream>>>(Aop, wob, bo, (float*)d_out);
}